// Round 3
// baseline (11.312 us; speedup 1.0000x reference)
//
#include <hip/hip_runtime.h>

// Decoder: separable-softmax resampling composite.
//
// Identities vs the reference:
//  - d2 = (r-src_r[i])^2 + (c-src_c[j])^2 is separable -> joint 4096-way
//    softmax factorizes: A@P = outer(er,ec)@P / (sum er * sum ec).
//  - softmax shift-invariance: exact min over i of (fr-x1-i*sr)^2 is at the
//    nearest grid point i* = clamp(rint((fr-x1)/sr),0,63) -> O(1) shift.
//  - outside-box outputs are constants -> whole-row early return (uniform),
//    per-column skip of the softmax loop.
//
// R2 structure: er broadcast via __shfl (no LDS, no first barrier); image
// column prefetched into registers BEFORE the er computation so cold HBM
// latency overlaps the exp work. Single barrier publishes u4.

__global__ __launch_bounds__(256) void decoder_kernel(
    const float* __restrict__ X,
    const float* __restrict__ images,
    float* __restrict__ out)
{
    const int b = blockIdx.x >> 8;   // batch 0..1
    const int r = blockIdx.x & 255;  // output row
    const int c = threadIdx.x;       // output column

    const float* dp = X + b * 19;
    const float x1 = rintf(dp[0] * 256.0f);
    const float x2 = rintf(dp[1] * 256.0f);
    const float y1 = rintf(dp[2] * 256.0f);
    const float y2 = rintf(dp[3] * 256.0f);

    const bool valid = (x1 >= 0.0f) && (y1 >= 0.0f) && (x2 <= 256.0f) &&
                       (y2 <= 256.0f) && (x2 > x1) && (y2 > y1);

    float* outb = out + (size_t)(b * 3) * 65536 + r * 256 + c;
    const float fr = (float)r;
    const float fc = (float)c;

    if (!valid) {  // uniform per block: safe early return (before any barrier)
        outb[0] = 0.0f; outb[65536] = 0.0f; outb[131072] = 0.0f;
        return;
    }
    const bool row_in = (fr >= x1) && (fr < x2);
    if (!row_in) { // whole row outside box -> constant 1.0 (uniform per block)
        outb[0] = 1.0f; outb[65536] = 1.0f; outb[131072] = 1.0f;
        return;
    }

    // argmax over dp[5..18], first-max wins (matches jnp.argmax)
    int idx = 0;
    float best = dp[5];
    #pragma unroll
    for (int k = 1; k < 14; ++k) {
        float v = dp[5 + k];
        if (v > best) { best = v; idx = k; }
    }

    const float sr = (x2 - x1) * 0.015625f;  // > 0
    const float sc = (y2 - y1) * 0.015625f;

    const int wave = c >> 6;
    const int lane = c & 63;

    // Prefetch this lane's image column into registers (independent of er).
    // wave ch in {0,1,2}, lane j: m_reg[i] = img[idx, ch, i, j]; coalesced
    // 256B per i across the wave. Unrolled -> constant indices -> VGPRs.
    float m_reg[64];
    if (wave < 3) {
        const float* Mc = images + ((size_t)idx * 4 + wave) * 4096 + lane;
        #pragma unroll
        for (int i = 0; i < 64; ++i) m_reg[i] = Mc[i * 64];
    }

    // Per-lane row weight er[lane] (O(1) shift at nearest grid point).
    float tsr = (fr - x1) / sr;
    float is  = fminf(fmaxf(rintf(tsr), 0.0f), 63.0f);
    float dmr = fr - (x1 + is * sr);
    float drl = fr - (x1 + (float)lane * sr);
    const float er_l = __expf(dmr * dmr - drl * drl);

    __shared__ float u4[64][4];    // u4[j][ch] = sum_i er[i]*M[ch][i][j]
    __shared__ float er_sum_sh;

    if (wave == 3) {
        // er_sum via 6-step butterfly, overlapped with the u-stage
        float v = er_l;
        #pragma unroll
        for (int off = 32; off > 0; off >>= 1) v += __shfl_xor(v, off, 64);
        if (lane == 0) er_sum_sh = v;
    } else {
        // u[ch][j] = sum_i er[i] * M[ch][i][j]; er broadcast via shuffle
        float acc0 = 0.0f, acc1 = 0.0f;
        #pragma unroll
        for (int i = 0; i < 64; i += 2) {
            acc0 = fmaf(__shfl(er_l, i,     64), m_reg[i],     acc0);
            acc1 = fmaf(__shfl(er_l, i + 1, 64), m_reg[i + 1], acc1);
        }
        u4[lane][wave] = acc0 + acc1;
    }
    __syncthreads();

    const bool col_in = (fc >= y1) && (fc < y2);
    if (!col_in) { // column outside box -> constant 1.0 (no barriers below)
        outb[0] = 1.0f; outb[65536] = 1.0f; outb[131072] = 1.0f;
        return;
    }

    // O(1) shift for the column direction
    float tsc = (fc - y1) / sc;
    float js  = fminf(fmaxf(rintf(tsc), 0.0f), 63.0f);
    float dmc = fc - (y1 + js * sc);
    float mc  = dmc * dmc;

    // column softmax fused with channel dots; 2-way split accumulator chains
    float ec0 = 0.0f, ec1 = 0.0f;
    float a00 = 0.0f, a01 = 0.0f, a10 = 0.0f, a11 = 0.0f, a20 = 0.0f, a21 = 0.0f;
    #pragma unroll
    for (int j = 0; j < 64; j += 2) {
        float dc0 = fc - (y1 + (float)j * sc);
        float dc1 = fc - (y1 + (float)(j + 1) * sc);
        float e0 = __expf(mc - dc0 * dc0);
        float e1 = __expf(mc - dc1 * dc1);
        float4 u0 = *reinterpret_cast<const float4*>(u4[j]);
        float4 u1 = *reinterpret_cast<const float4*>(u4[j + 1]);
        ec0 += e0;                    ec1 += e1;
        a00 = fmaf(u0.x, e0, a00);    a01 = fmaf(u1.x, e1, a01);
        a10 = fmaf(u0.y, e0, a10);    a11 = fmaf(u1.y, e1, a11);
        a20 = fmaf(u0.z, e0, a20);    a21 = fmaf(u1.z, e1, a21);
    }
    const float inv = 1.0f / (er_sum_sh * (ec0 + ec1));
    outb[0]      = (a00 + a01) * inv;
    outb[65536]  = (a10 + a11) * inv;
    outb[131072] = (a20 + a21) * inv;
}

extern "C" void kernel_launch(void* const* d_in, const int* in_sizes, int n_in,
                              void* d_out, int out_size, void* d_ws, size_t ws_size,
                              hipStream_t stream) {
    const float* X      = (const float*)d_in[0];   // (2,1,19) f32
    const float* images = (const float*)d_in[1];   // (14,4,64,64) f32
    float* out          = (float*)d_out;           // (2,3,256,256) f32

    decoder_kernel<<<dim3(512), dim3(256), 0, stream>>>(X, images, out);
}

// Round 4
// 10.776 us; speedup vs baseline: 1.0498x; 1.0498x over previous
//
#include <hip/hip_runtime.h>

// Decoder: separable-softmax resampling composite.  (R3 = revert to R1 — best
// measured; R2's shfl/prefetch variant regressed: ds_permute is not cheaper
// than broadcast LDS reads, and the 64-reg prefetch cut occupancy.)
//
// Key identities vs the reference:
//  - d2 = (r-src_r[i])^2 + (c-src_c[j])^2 is separable, so the joint 4096-way
//    softmax factorizes: A@P = outer(er,ec)@P / (sum er * sum ec).
//  - softmax is shift-invariant; the exact min over i of (fr-x1-i*sr)^2 is at
//    the nearest grid point i* = clamp(rint((fr-x1)/sr),0,63) -> O(1) shift.
//  - outputs outside the box are constant (1.0 if valid else 0.0) -> skip all
//    softmax work for those rows/columns.

__global__ __launch_bounds__(256) void decoder_kernel(
    const float* __restrict__ X,
    const float* __restrict__ images,
    float* __restrict__ out)
{
    const int b = blockIdx.x >> 8;   // batch 0..1
    const int r = blockIdx.x & 255;  // output row
    const int c = threadIdx.x;       // output column

    const float* dp = X + b * 19;
    const float x1 = rintf(dp[0] * 256.0f);
    const float x2 = rintf(dp[1] * 256.0f);
    const float y1 = rintf(dp[2] * 256.0f);
    const float y2 = rintf(dp[3] * 256.0f);

    const bool valid = (x1 >= 0.0f) && (y1 >= 0.0f) && (x2 <= 256.0f) &&
                       (y2 <= 256.0f) && (x2 > x1) && (y2 > y1);

    float* outb = out + (size_t)(b * 3) * 65536 + r * 256 + c;
    const float fr = (float)r;
    const float fc = (float)c;

    if (!valid) {  // uniform per block: safe early return (before any barrier)
        outb[0] = 0.0f; outb[65536] = 0.0f; outb[131072] = 0.0f;
        return;
    }
    const bool row_in = (fr >= x1) && (fr < x2);
    if (!row_in) { // whole row outside box -> constant 1.0 (uniform per block)
        outb[0] = 1.0f; outb[65536] = 1.0f; outb[131072] = 1.0f;
        return;
    }

    // argmax over dp[5..18], first-max wins (matches jnp.argmax)
    int idx = 0;
    float best = dp[5];
    #pragma unroll
    for (int k = 1; k < 14; ++k) {
        float v = dp[5 + k];
        if (v > best) { best = v; idx = k; }
    }

    const float sr = (x2 - x1) * 0.015625f;  // > 0 (x2>x1, whole numbers)
    const float sc = (y2 - y1) * 0.015625f;

    __shared__ float er[64];       // row weights exp(mr - dr2[i])
    __shared__ float u4[64][4];    // u4[j][ch] = sum_i er[i]*M[ch][i][j] (ch 0..2)
    __shared__ float er_sum_sh;

    if (c < 64) {
        // O(1) shift: nearest source row to fr
        float ts = (fr - x1) / sr;
        float is = fminf(fmaxf(rintf(ts), 0.0f), 63.0f);
        float dm = fr - (x1 + is * sr);
        float mr = dm * dm;
        float dr = fr - (x1 + (float)c * sr);
        er[c] = __expf(mr - dr * dr);
    }
    __syncthreads();

    const int wave = c >> 6;
    const int lane = c & 63;
    if (wave == 3) {
        // wave 3: er_sum via 6-step butterfly, overlapped with the u-stage
        float v = er[lane];
        #pragma unroll
        for (int off = 32; off > 0; off >>= 1) v += __shfl_xor(v, off, 64);
        if (lane == 0) er_sum_sh = v;
    } else {
        // waves 0..2: u4[j][ch] = sum_i er[i] * img[idx,ch,i,j]
        const int ch = wave;
        const int j  = lane;
        const float* Mc = images + ((size_t)idx * 4 + ch) * 4096 + j;
        float acc = 0.0f;
        #pragma unroll
        for (int i = 0; i < 64; ++i) acc = fmaf(er[i], Mc[i * 64], acc);
        u4[j][ch] = acc;
    }
    __syncthreads();

    const bool col_in = (fc >= y1) && (fc < y2);
    if (!col_in) { // column outside box -> constant 1.0 (no barriers below)
        outb[0] = 1.0f; outb[65536] = 1.0f; outb[131072] = 1.0f;
        return;
    }

    // O(1) shift for the column direction
    float ts = (fc - y1) / sc;
    float js = fminf(fmaxf(rintf(ts), 0.0f), 63.0f);
    float dm = fc - (y1 + js * sc);
    float mc = dm * dm;

    // column softmax fused with channel dots; 2-way split accumulator chains
    float ec0 = 0.0f, ec1 = 0.0f;
    float a00 = 0.0f, a01 = 0.0f, a10 = 0.0f, a11 = 0.0f, a20 = 0.0f, a21 = 0.0f;
    #pragma unroll
    for (int j = 0; j < 64; j += 2) {
        float dc0 = fc - (y1 + (float)j * sc);
        float dc1 = fc - (y1 + (float)(j + 1) * sc);
        float e0 = __expf(mc - dc0 * dc0);
        float e1 = __expf(mc - dc1 * dc1);
        float4 u0 = *reinterpret_cast<const float4*>(u4[j]);
        float4 u1 = *reinterpret_cast<const float4*>(u4[j + 1]);
        ec0 += e0;                    ec1 += e1;
        a00 = fmaf(u0.x, e0, a00);    a01 = fmaf(u1.x, e1, a01);
        a10 = fmaf(u0.y, e0, a10);    a11 = fmaf(u1.y, e1, a11);
        a20 = fmaf(u0.z, e0, a20);    a21 = fmaf(u1.z, e1, a21);
    }
    const float inv = 1.0f / (er_sum_sh * (ec0 + ec1));
    outb[0]      = (a00 + a01) * inv;
    outb[65536]  = (a10 + a11) * inv;
    outb[131072] = (a20 + a21) * inv;
}

extern "C" void kernel_launch(void* const* d_in, const int* in_sizes, int n_in,
                              void* d_out, int out_size, void* d_ws, size_t ws_size,
                              hipStream_t stream) {
    const float* X      = (const float*)d_in[0];   // (2,1,19) f32
    const float* images = (const float*)d_in[1];   // (14,4,64,64) f32
    float* out          = (float*)d_out;           // (2,3,256,256) f32

    decoder_kernel<<<dim3(512), dim3(256), 0, stream>>>(X, images, out);
}